// Round 1
// baseline (461.557 us; speedup 1.0000x reference)
//
#include <hip/hip_runtime.h>
#include <stdint.h>

#define DD 128

// ---- order-preserving float<->uint encoding for atomic max ----
// enc is strictly increasing in float order; enc(any finite float) > 0,
// so 0 works as "empty" sentinel AND identity for atomicMax(uint).
__device__ __forceinline__ uint32_t enc_f32(float f) {
    uint32_t u = __float_as_uint(f);
    return (u & 0x80000000u) ? ~u : (u | 0x80000000u);
}
__device__ __forceinline__ float dec_f32(uint32_t u) {
    u = (u & 0x80000000u) ? (u ^ 0x80000000u) : ~u;
    return __uint_as_float(u);
}

// ---- scatter-max: one thread per (edge, dim) ----
__global__ __launch_bounds__(256) void scatter_max_k(
    const float* __restrict__ x1, const int* __restrict__ adj,
    uint32_t* __restrict__ x2enc, int n_edges, int n_nodes)
{
    int gtid = blockIdx.x * 256 + threadIdx.x;
    int e = gtid >> 7;
    int d = gtid & 127;
    if (e >= n_edges) return;
    int src = adj[e];
    int dst = adj[n_edges + e];
    if ((unsigned)src >= (unsigned)n_nodes) return;  // defensive
    if ((unsigned)dst >= (unsigned)n_nodes) return;
    float v = x1[(size_t)src * DD + d];
    atomicMax(&x2enc[(size_t)dst * DD + d], enc_f32(v));
}

// ---- fused decode + residual + relu(xW1+b1) @ W2 + b2 ----
// Block: 256 threads (4 waves). LDS: W1 (64KB) + W2 (64KB) + 32-row tile (16KB).
// Each wave owns 8 rows; lane c computes output cols c and c+64.
__global__ __launch_bounds__(256) void mlp_k(
    const float* __restrict__ x1, const uint32_t* __restrict__ x2enc,
    const float* __restrict__ W1, const float* __restrict__ b1,
    const float* __restrict__ W2, const float* __restrict__ b2,
    float* __restrict__ out, int n_rows)
{
    __shared__ float sW1[DD * DD];   // 64 KB
    __shared__ float sW2[DD * DD];   // 64 KB
    __shared__ float sx[32 * DD];    // 16 KB, reused in-place for h

    const int tid  = threadIdx.x;
    const int wave = tid >> 6;
    const int lane = tid & 63;
    const int c0   = lane;

    // stage weights (coalesced; each thread 64 elems per matrix)
    for (int i = tid; i < DD * DD; i += 256) {
        sW1[i] = W1[i];
        sW2[i] = W2[i];
    }

    const float b1a = b1[c0], b1b = b1[c0 + 64];
    const float b2a = b2[c0], b2b = b2[c0 + 64];

    const int row0 = blockIdx.x * 32;

    // stage xin = x1 + decoded segment-max (0 if empty segment)
    for (int i = tid; i < 32 * DD; i += 256) {
        size_t g = (size_t)row0 * DD + i;
        float v = 0.f;
        if (row0 + (i >> 7) < n_rows) {
            uint32_t e = x2enc[g];
            float m = (e == 0u) ? 0.f : dec_f32(e);
            v = x1[g] + m;
        }
        sx[i] = v;
    }
    __syncthreads();   // W + x tile visible to all

    const int r0 = wave * 8;   // wave-private 8 rows within the 32-row tile

    // ---- layer 1 ----
    float acc0[8], acc1[8];
    #pragma unroll
    for (int r = 0; r < 8; ++r) { acc0[r] = b1a; acc1[r] = b1b; }

    #pragma unroll 4
    for (int k = 0; k < DD; ++k) {
        float w0 = sW1[k * DD + c0];
        float w1 = sW1[k * DD + c0 + 64];
        #pragma unroll
        for (int r = 0; r < 8; ++r) {
            float xv = sx[(r0 + r) * DD + k];   // wave-uniform broadcast
            acc0[r] = fmaf(xv, w0, acc0[r]);
            acc1[r] = fmaf(xv, w1, acc1[r]);
        }
    }

    // relu; write h back into sx (each wave touches only its own 8 rows,
    // and all of this wave's reads of those rows precede the writes)
    #pragma unroll
    for (int r = 0; r < 8; ++r) {
        sx[(r0 + r) * DD + c0]      = fmaxf(acc0[r], 0.f);
        sx[(r0 + r) * DD + c0 + 64] = fmaxf(acc1[r], 0.f);
    }
    __syncthreads();

    // ---- layer 2 ----
    #pragma unroll
    for (int r = 0; r < 8; ++r) { acc0[r] = b2a; acc1[r] = b2b; }

    #pragma unroll 4
    for (int k = 0; k < DD; ++k) {
        float w0 = sW2[k * DD + c0];
        float w1 = sW2[k * DD + c0 + 64];
        #pragma unroll
        for (int r = 0; r < 8; ++r) {
            float hv = sx[(r0 + r) * DD + k];
            acc0[r] = fmaf(hv, w0, acc0[r]);
            acc1[r] = fmaf(hv, w1, acc1[r]);
        }
    }

    #pragma unroll
    for (int r = 0; r < 8; ++r) {
        int row = row0 + r0 + r;
        if (row < n_rows) {
            out[(size_t)row * DD + c0]      = acc0[r];
            out[(size_t)row * DD + c0 + 64] = acc1[r];
        }
    }
}

extern "C" void kernel_launch(void* const* d_in, const int* in_sizes, int n_in,
                              void* d_out, int out_size, void* d_ws, size_t ws_size,
                              hipStream_t stream) {
    const float* x1 = (const float*)d_in[0];
    const int*   adj = (const int*)d_in[1];     // harness passes integers as int32
    const float* W1 = (const float*)d_in[2];
    const float* b1 = (const float*)d_in[3];
    const float* W2 = (const float*)d_in[4];
    const float* b2 = (const float*)d_in[5];
    float* out = (float*)d_out;

    const int n_nodes = in_sizes[0] / DD;       // 50000
    const int n_edges = in_sizes[1] / 2;        // 800000

    uint32_t* x2enc = (uint32_t*)d_ws;          // 25.6 MB scratch

    hipMemsetAsync(x2enc, 0, (size_t)n_nodes * DD * sizeof(uint32_t), stream);

    {
        long long total = (long long)n_edges * DD;
        int blocks = (int)((total + 255) / 256);
        scatter_max_k<<<blocks, 256, 0, stream>>>(x1, adj, x2enc, n_edges, n_nodes);
    }
    {
        int blocks = (n_nodes + 31) / 32;
        mlp_k<<<blocks, 256, 0, stream>>>(x1, x2enc, W1, b1, W2, b2, out, n_nodes);
    }
}

// Round 2
// 367.040 us; speedup vs baseline: 1.2575x; 1.2575x over previous
//
#include <hip/hip_runtime.h>
#include <stdint.h>
#include <math.h>

#define DD 128

// ============ CSR build: histogram -> exclusive scan -> fill ============

__global__ __launch_bounds__(256) void hist_k(
    const int* __restrict__ adj, int* __restrict__ counts,
    int n_edges, int n_nodes)
{
    int e = blockIdx.x * 256 + threadIdx.x;
    if (e >= n_edges) return;
    int dst = adj[n_edges + e];
    if ((unsigned)dst >= (unsigned)n_nodes) return;  // defensive
    atomicAdd(&counts[dst], 1);
}

// single-block exclusive scan over n counts -> row_start[0..n], cursor copy
__global__ __launch_bounds__(1024) void scan_k(
    const int* __restrict__ counts, int* __restrict__ row_start,
    int* __restrict__ cursor, int n)
{
    __shared__ int wsum[16];
    __shared__ int base_sh;
    const int tid = threadIdx.x;
    const int wid = tid >> 6, lane = tid & 63;
    if (tid == 0) base_sh = 0;
    __syncthreads();
    for (int chunk = 0; chunk < n; chunk += 1024) {
        int i = chunk + tid;
        int v = (i < n) ? counts[i] : 0;
        int incl = v;
        #pragma unroll
        for (int off = 1; off < 64; off <<= 1) {
            int t = __shfl_up(incl, off);
            if (lane >= off) incl += t;
        }
        if (lane == 63) wsum[wid] = incl;
        __syncthreads();
        if (wid == 0) {
            int s = (lane < 16) ? wsum[lane] : 0;
            #pragma unroll
            for (int off = 1; off < 16; off <<= 1) {
                int t = __shfl_up(s, off);
                if (lane >= off) s += t;
            }
            if (lane < 16) wsum[lane] = s;   // inclusive per-wave sums
        }
        __syncthreads();
        int base = base_sh;
        int wave_off = wid ? wsum[wid - 1] : 0;
        int excl = base + wave_off + incl - v;
        if (i < n) { row_start[i] = excl; cursor[i] = excl; }
        int chunk_total = wsum[15];
        __syncthreads();                 // everyone done reading base_sh/wsum
        if (tid == 0) base_sh = base + chunk_total;
        __syncthreads();
    }
    if (tid == 0) row_start[n] = base_sh;
}

__global__ __launch_bounds__(256) void fill_k(
    const int* __restrict__ adj, int* __restrict__ cursor,
    int* __restrict__ csr_src, int n_edges, int n_nodes)
{
    int e = blockIdx.x * 256 + threadIdx.x;
    if (e >= n_edges) return;
    int src = adj[e];
    int dst = adj[n_edges + e];
    if ((unsigned)src >= (unsigned)n_nodes) return;
    if ((unsigned)dst >= (unsigned)n_nodes) return;
    int slot = atomicAdd(&cursor[dst], 1);   // absolute index (cursor=row_start copy)
    csr_src[slot] = src;
}

// ============ per-node gather-max, fused residual: xin = x1 + segmax ============
// 2 nodes per 256-thread block; 128 threads per node (one per dim).
__global__ __launch_bounds__(256) void gather_max_k(
    const float* __restrict__ x1, const int* __restrict__ row_start,
    const int* __restrict__ csr_src, float* __restrict__ xin, int n_nodes)
{
    int node = blockIdx.x * 2 + (threadIdx.x >> 7);
    int d = threadIdx.x & 127;
    if (node >= n_nodes) return;
    int s = row_start[node], e = row_start[node + 1];
    float m0 = -INFINITY, m1 = -INFINITY;
    int i = s;
    for (; i + 1 < e; i += 2) {          // 2 gathers in flight
        int s0 = csr_src[i], s1 = csr_src[i + 1];
        m0 = fmaxf(m0, x1[(size_t)s0 * DD + d]);
        m1 = fmaxf(m1, x1[(size_t)s1 * DD + d]);
    }
    if (i < e) m0 = fmaxf(m0, x1[(size_t)csr_src[i] * DD + d]);
    float m = fmaxf(m0, m1);
    float add = (s < e) ? m : 0.f;       // empty segment -> 0
    xin[(size_t)node * DD + d] = x1[(size_t)node * DD + d] + add;
}

// ============ fused 2-layer MLP: relu(xin@W1+b1)@W2+b2 ============
__global__ __launch_bounds__(256) void mlp_k(
    const float* __restrict__ xin,
    const float* __restrict__ W1, const float* __restrict__ b1,
    const float* __restrict__ W2, const float* __restrict__ b2,
    float* __restrict__ out, int n_rows)
{
    __shared__ float sW1[DD * DD];   // 64 KB
    __shared__ float sW2[DD * DD];   // 64 KB
    __shared__ float sx[32 * DD];    // 16 KB, reused in-place for h

    const int tid  = threadIdx.x;
    const int wave = tid >> 6;
    const int lane = tid & 63;
    const int c0   = lane;

    // stage weights (float4 coalesced)
    const float4* W1_4 = (const float4*)W1;
    const float4* W2_4 = (const float4*)W2;
    float4* sW1_4 = (float4*)sW1;
    float4* sW2_4 = (float4*)sW2;
    for (int i = tid; i < DD * DD / 4; i += 256) {
        sW1_4[i] = W1_4[i];
        sW2_4[i] = W2_4[i];
    }

    const float b1a = b1[c0], b1b = b1[c0 + 64];
    const float b2a = b2[c0], b2b = b2[c0 + 64];

    const int row0 = blockIdx.x * 32;

    // stage 32-row xin tile (float4)
    const float4* xin4 = (const float4*)(xin + (size_t)row0 * DD);
    float4* sx4 = (float4*)sx;
    for (int i = tid; i < 32 * DD / 4; i += 256) {
        int r = i >> 5;                          // 32 float4 per row
        float4 v = make_float4(0.f, 0.f, 0.f, 0.f);
        if (row0 + r < n_rows) v = xin4[i];
        sx4[i] = v;
    }
    __syncthreads();

    const int r0 = wave * 8;   // wave-private 8 rows within the 32-row tile

    // ---- layer 1 ----
    float acc0[8], acc1[8];
    #pragma unroll
    for (int r = 0; r < 8; ++r) { acc0[r] = b1a; acc1[r] = b1b; }

    #pragma unroll 4
    for (int k = 0; k < DD; ++k) {
        float w0 = sW1[k * DD + c0];
        float w1 = sW1[k * DD + c0 + 64];
        #pragma unroll
        for (int r = 0; r < 8; ++r) {
            float xv = sx[(r0 + r) * DD + k];
            acc0[r] = fmaf(xv, w0, acc0[r]);
            acc1[r] = fmaf(xv, w1, acc1[r]);
        }
    }

    #pragma unroll
    for (int r = 0; r < 8; ++r) {
        sx[(r0 + r) * DD + c0]      = fmaxf(acc0[r], 0.f);
        sx[(r0 + r) * DD + c0 + 64] = fmaxf(acc1[r], 0.f);
    }
    __syncthreads();

    // ---- layer 2 ----
    #pragma unroll
    for (int r = 0; r < 8; ++r) { acc0[r] = b2a; acc1[r] = b2b; }

    #pragma unroll 4
    for (int k = 0; k < DD; ++k) {
        float w0 = sW2[k * DD + c0];
        float w1 = sW2[k * DD + c0 + 64];
        #pragma unroll
        for (int r = 0; r < 8; ++r) {
            float hv = sx[(r0 + r) * DD + k];
            acc0[r] = fmaf(hv, w0, acc0[r]);
            acc1[r] = fmaf(hv, w1, acc1[r]);
        }
    }

    #pragma unroll
    for (int r = 0; r < 8; ++r) {
        int row = row0 + r0 + r;
        if (row < n_rows) {
            out[(size_t)row * DD + c0]      = acc0[r];
            out[(size_t)row * DD + c0 + 64] = acc1[r];
        }
    }
}

extern "C" void kernel_launch(void* const* d_in, const int* in_sizes, int n_in,
                              void* d_out, int out_size, void* d_ws, size_t ws_size,
                              hipStream_t stream) {
    const float* x1  = (const float*)d_in[0];
    const int*   adj = (const int*)d_in[1];
    const float* W1  = (const float*)d_in[2];
    const float* b1  = (const float*)d_in[3];
    const float* W2  = (const float*)d_in[4];
    const float* b2  = (const float*)d_in[5];
    float* out = (float*)d_out;

    const int n_nodes = in_sizes[0] / DD;   // 50000
    const int n_edges = in_sizes[1] / 2;    // 800000

    // workspace layout
    char* ws = (char*)d_ws;
    size_t off = 0;
    float* xin      = (float*)(ws + off); off += (size_t)n_nodes * DD * sizeof(float);
    int*   row_start= (int*)(ws + off);   off += (size_t)(n_nodes + 1) * sizeof(int);
    int*   cursor   = (int*)(ws + off);   off += (size_t)n_nodes * sizeof(int);
    int*   counts   = (int*)(ws + off);   off += (size_t)n_nodes * sizeof(int);
    int*   csr_src  = (int*)(ws + off);   off += (size_t)n_edges * sizeof(int);

    hipMemsetAsync(counts, 0, (size_t)n_nodes * sizeof(int), stream);

    int eb = (n_edges + 255) / 256;
    hist_k<<<eb, 256, 0, stream>>>(adj, counts, n_edges, n_nodes);
    scan_k<<<1, 1024, 0, stream>>>(counts, row_start, cursor, n_nodes);
    fill_k<<<eb, 256, 0, stream>>>(adj, cursor, csr_src, n_edges, n_nodes);
    gather_max_k<<<(n_nodes + 1) / 2, 256, 0, stream>>>(x1, row_start, csr_src, xin, n_nodes);
    mlp_k<<<(n_nodes + 31) / 32, 256, 0, stream>>>(xin, W1, b1, W2, b2, out, n_nodes);
}

// Round 3
// 182.295 us; speedup vs baseline: 2.5319x; 2.0134x over previous
//
#include <hip/hip_runtime.h>
#include <stdint.h>
#include <math.h>

#define DD 128
#define ROWS 128   // rows per MLP block

typedef unsigned short u16;
typedef unsigned int   u32;
typedef __attribute__((ext_vector_type(8))) short bf16x8;
typedef __attribute__((ext_vector_type(4))) float f32x4;

__device__ __forceinline__ u16 f2bf(float f) {   // RNE f32 -> bf16
    u32 u = __float_as_uint(f);
    return (u16)((u + 0x7fffu + ((u >> 16) & 1u)) >> 16);
}
// T2 swizzle: byte offset within a [row][256B] tile, XOR bits 4-6 by row&7
__device__ __forceinline__ int swz(int row, int byte_in_row) {
    return row * 256 + (byte_in_row ^ ((row & 7) << 4));
}

// ============ CSR build ============

__global__ __launch_bounds__(256) void hist_k(
    const int* __restrict__ adj, int* __restrict__ counts,
    int n_edges, int n_nodes)
{
    int e = blockIdx.x * 256 + threadIdx.x;
    if (e >= n_edges) return;
    int dst = adj[n_edges + e];
    if ((unsigned)dst >= (unsigned)n_nodes) return;
    atomicAdd(&counts[dst], 1);
}

// phase A: per-256-block sums
__global__ __launch_bounds__(256) void reduce_counts_k(
    const int* __restrict__ counts, int* __restrict__ block_sums, int n)
{
    int i = blockIdx.x * 256 + threadIdx.x;
    int v = (i < n) ? counts[i] : 0;
    #pragma unroll
    for (int off = 32; off >= 1; off >>= 1) v += __shfl_down(v, off);
    __shared__ int ws[4];
    if ((threadIdx.x & 63) == 0) ws[threadIdx.x >> 6] = v;
    __syncthreads();
    if (threadIdx.x == 0) block_sums[blockIdx.x] = ws[0] + ws[1] + ws[2] + ws[3];
}

// phase B: single tiny block scans <=256 block sums -> exclusive offsets + total
__global__ __launch_bounds__(256) void scan_sums_k(
    const int* __restrict__ block_sums, int* __restrict__ block_off,
    int* __restrict__ row_start, int nb, int n)
{
    int tid = threadIdx.x, wid = tid >> 6, lane = tid & 63;
    int v = (tid < nb) ? block_sums[tid] : 0;
    int incl = v;
    #pragma unroll
    for (int off = 1; off < 64; off <<= 1) {
        int t = __shfl_up(incl, off);
        if (lane >= off) incl += t;
    }
    __shared__ int ws[4];
    if (lane == 63) ws[wid] = incl;
    __syncthreads();
    int woff = 0;
    #pragma unroll
    for (int j = 0; j < 4; ++j) if (j < wid) woff += ws[j];
    if (tid < nb) block_off[tid] = woff + incl - v;
    if (tid == 0) row_start[n] = ws[0] + ws[1] + ws[2] + ws[3];
}

// phase C: per-block exclusive scan + global offset -> row_start, cursor
__global__ __launch_bounds__(256) void scan_write_k(
    const int* __restrict__ counts, const int* __restrict__ block_off,
    int* __restrict__ row_start, int* __restrict__ cursor, int n)
{
    int tid = threadIdx.x, wid = tid >> 6, lane = tid & 63;
    int i = blockIdx.x * 256 + tid;
    int v = (i < n) ? counts[i] : 0;
    int incl = v;
    #pragma unroll
    for (int off = 1; off < 64; off <<= 1) {
        int t = __shfl_up(incl, off);
        if (lane >= off) incl += t;
    }
    __shared__ int ws[4];
    if (lane == 63) ws[wid] = incl;
    __syncthreads();
    int woff = 0;
    #pragma unroll
    for (int j = 0; j < 4; ++j) if (j < wid) woff += ws[j];
    int excl = block_off[blockIdx.x] + woff + incl - v;
    if (i < n) { row_start[i] = excl; cursor[i] = excl; }
}

__global__ __launch_bounds__(256) void fill_k(
    const int* __restrict__ adj, int* __restrict__ cursor,
    int* __restrict__ csr_src, int n_edges, int n_nodes)
{
    int e = blockIdx.x * 256 + threadIdx.x;
    if (e >= n_edges) return;
    int src = adj[e];
    int dst = adj[n_edges + e];
    if ((unsigned)src >= (unsigned)n_nodes) return;
    if ((unsigned)dst >= (unsigned)n_nodes) return;
    int slot = atomicAdd(&cursor[dst], 1);
    csr_src[slot] = src;
}

// ============ gather-max + residual -> bf16 xin ============
// 8 nodes per 256-thread block; 32 threads per node, float4 per thread.
__global__ __launch_bounds__(256) void gather_max_k(
    const float* __restrict__ x1, const int* __restrict__ row_start,
    const int* __restrict__ csr_src, u16* __restrict__ xin, int n_nodes)
{
    int node = blockIdx.x * 8 + (threadIdx.x >> 5);
    int q = threadIdx.x & 31;          // float4 index within row
    if (node >= n_nodes) return;
    int s = row_start[node], e = row_start[node + 1];
    const float4* x4 = (const float4*)x1;
    float4 m0 = make_float4(-INFINITY, -INFINITY, -INFINITY, -INFINITY);
    float4 m1 = m0, m2 = m0, m3 = m0;
    int i = s;
    for (; i + 3 < e; i += 4) {
        int s0 = csr_src[i], s1 = csr_src[i+1], s2 = csr_src[i+2], s3 = csr_src[i+3];
        float4 v0 = x4[(size_t)s0 * 32 + q];
        float4 v1 = x4[(size_t)s1 * 32 + q];
        float4 v2 = x4[(size_t)s2 * 32 + q];
        float4 v3 = x4[(size_t)s3 * 32 + q];
        m0.x=fmaxf(m0.x,v0.x); m0.y=fmaxf(m0.y,v0.y); m0.z=fmaxf(m0.z,v0.z); m0.w=fmaxf(m0.w,v0.w);
        m1.x=fmaxf(m1.x,v1.x); m1.y=fmaxf(m1.y,v1.y); m1.z=fmaxf(m1.z,v1.z); m1.w=fmaxf(m1.w,v1.w);
        m2.x=fmaxf(m2.x,v2.x); m2.y=fmaxf(m2.y,v2.y); m2.z=fmaxf(m2.z,v2.z); m2.w=fmaxf(m2.w,v2.w);
        m3.x=fmaxf(m3.x,v3.x); m3.y=fmaxf(m3.y,v3.y); m3.z=fmaxf(m3.z,v3.z); m3.w=fmaxf(m3.w,v3.w);
    }
    for (; i < e; ++i) {
        int s0 = csr_src[i];
        float4 v0 = x4[(size_t)s0 * 32 + q];
        m0.x=fmaxf(m0.x,v0.x); m0.y=fmaxf(m0.y,v0.y); m0.z=fmaxf(m0.z,v0.z); m0.w=fmaxf(m0.w,v0.w);
    }
    m0.x=fmaxf(fmaxf(m0.x,m1.x),fmaxf(m2.x,m3.x));
    m0.y=fmaxf(fmaxf(m0.y,m1.y),fmaxf(m2.y,m3.y));
    m0.z=fmaxf(fmaxf(m0.z,m1.z),fmaxf(m2.z,m3.z));
    m0.w=fmaxf(fmaxf(m0.w,m1.w),fmaxf(m2.w,m3.w));
    float4 self = x4[(size_t)node * 32 + q];
    float4 r;
    if (s < e) { r.x=self.x+m0.x; r.y=self.y+m0.y; r.z=self.z+m0.z; r.w=self.w+m0.w; }
    else       { r = self; }
    uint2 p;
    p.x = (u32)f2bf(r.x) | ((u32)f2bf(r.y) << 16);
    p.y = (u32)f2bf(r.z) | ((u32)f2bf(r.w) << 16);
    ((uint2*)xin)[(size_t)node * 32 + q] = p;
}

// ============ W -> bf16, transposed [c][k], pre-swizzled for linear LDS staging ============
__global__ __launch_bounds__(256) void wprep_k(
    const float* __restrict__ W1, const float* __restrict__ W2,
    u16* __restrict__ W1T, u16* __restrict__ W2T)
{
    int t = blockIdx.x * 256 + threadIdx.x;   // 0..4095
    if (t >= 4096) return;
    int m = t >> 11;                          // 0: W1, 1: W2
    int idx = t & 2047;
    int c = idx >> 4, k8 = idx & 15;          // c: out col, k8: chunk of 8 k's
    const float* W = m ? W2 : W1;
    u16* WT = m ? W2T : W1T;
    u16 tmp[8];
    #pragma unroll
    for (int j = 0; j < 8; ++j) tmp[j] = f2bf(W[(k8 * 8 + j) * DD + c]);
    uint4 v;
    v.x = (u32)tmp[0] | ((u32)tmp[1] << 16);
    v.y = (u32)tmp[2] | ((u32)tmp[3] << 16);
    v.z = (u32)tmp[4] | ((u32)tmp[5] << 16);
    v.w = (u32)tmp[6] | ((u32)tmp[7] << 16);
    *(uint4*)((char*)WT + swz(c, k8 * 16)) = v;
}

// ============ MFMA MLP: out = relu(xin@W1+b1)@W2+b2 ============
// 256 threads (4 waves), 128 rows/block. LDS 64KB -> 2 blocks/CU.
__global__ __launch_bounds__(256, 2) void mlp_mfma_k(
    const u16* __restrict__ xin,
    const u16* __restrict__ W1T, const float* __restrict__ b1,
    const u16* __restrict__ W2T, const float* __restrict__ b2,
    float* __restrict__ out, int n_rows)
{
    __shared__ uint4 sXq[ROWS * 16];   // 32KB swizzled bf16 [128][128], reused for h
    __shared__ uint4 sWq[128 * 16];    // 32KB swizzled bf16 W^T [c][k]
    char* sX = (char*)sXq;
    char* sW = (char*)sWq;

    const int tid  = threadIdx.x;
    const int wave = tid >> 6;
    const int lane = tid & 63;
    const int lhi  = lane >> 4, llo = lane & 15;
    const int row0 = blockIdx.x * ROWS;

    // stage X (swizzled) + W1T (linear, pre-swizzled)
    {
        const uint4* src = (const uint4*)xin;
        #pragma unroll
        for (int i = tid; i < ROWS * 16; i += 256) {
            int r = i >> 4, c8 = i & 15;
            uint4 v = make_uint4(0, 0, 0, 0);
            if (row0 + r < n_rows) v = src[(size_t)(row0 + r) * 16 + c8];
            *(uint4*)(sX + swz(r, c8 * 16)) = v;
        }
        const uint4* wsrc = (const uint4*)W1T;
        #pragma unroll
        for (int i = tid; i < 2048; i += 256) sWq[i] = wsrc[i];
    }
    __syncthreads();

    const int wrow0 = wave * 32;   // this wave's 32 rows (block-local)

    // ---- layer 1 ----
    f32x4 acc[2][8];
    #pragma unroll
    for (int mi = 0; mi < 2; ++mi)
        #pragma unroll
        for (int nj = 0; nj < 8; ++nj)
            acc[mi][nj] = (f32x4){0.f, 0.f, 0.f, 0.f};

    #pragma unroll
    for (int kstep = 0; kstep < 4; ++kstep) {
        int kb = (kstep * 32 + lhi * 8) * 2;   // byte offset along k
        int ra = wrow0 + llo, rb = wrow0 + 16 + llo;
        bf16x8 a0 = *(const bf16x8*)(sX + swz(ra, kb));
        bf16x8 a1 = *(const bf16x8*)(sX + swz(rb, kb));
        #pragma unroll
        for (int nj = 0; nj < 8; ++nj) {
            int c = nj * 16 + llo;
            bf16x8 b = *(const bf16x8*)(sW + swz(c, kb));
            acc[0][nj] = __builtin_amdgcn_mfma_f32_16x16x32_bf16(a0, b, acc[0][nj], 0, 0, 0);
            acc[1][nj] = __builtin_amdgcn_mfma_f32_16x16x32_bf16(a1, b, acc[1][nj], 0, 0, 0);
        }
    }

    // bias + relu -> h (bf16) back into sX (wave-private rows)
    #pragma unroll
    for (int nj = 0; nj < 8; ++nj) {
        int col = nj * 16 + llo;
        float bv = b1[col];
        #pragma unroll
        for (int mi = 0; mi < 2; ++mi) {
            #pragma unroll
            for (int r = 0; r < 4; ++r) {
                int row = wrow0 + mi * 16 + lhi * 4 + r;   // C/D: col=lane&15, row=(lane>>4)*4+reg
                float h = fmaxf(acc[mi][nj][r] + bv, 0.f);
                *(u16*)(sX + swz(row, col * 2)) = f2bf(h);
            }
        }
    }
    __syncthreads();

    // stage W2T
    {
        const uint4* wsrc = (const uint4*)W2T;
        #pragma unroll
        for (int i = tid; i < 2048; i += 256) sWq[i] = wsrc[i];
    }
    __syncthreads();

    // ---- layer 2 ----
    #pragma unroll
    for (int mi = 0; mi < 2; ++mi)
        #pragma unroll
        for (int nj = 0; nj < 8; ++nj)
            acc[mi][nj] = (f32x4){0.f, 0.f, 0.f, 0.f};

    #pragma unroll
    for (int kstep = 0; kstep < 4; ++kstep) {
        int kb = (kstep * 32 + lhi * 8) * 2;
        int ra = wrow0 + llo, rb = wrow0 + 16 + llo;
        bf16x8 a0 = *(const bf16x8*)(sX + swz(ra, kb));
        bf16x8 a1 = *(const bf16x8*)(sX + swz(rb, kb));
        #pragma unroll
        for (int nj = 0; nj < 8; ++nj) {
            int c = nj * 16 + llo;
            bf16x8 b = *(const bf16x8*)(sW + swz(c, kb));
            acc[0][nj] = __builtin_amdgcn_mfma_f32_16x16x32_bf16(a0, b, acc[0][nj], 0, 0, 0);
            acc[1][nj] = __builtin_amdgcn_mfma_f32_16x16x32_bf16(a1, b, acc[1][nj], 0, 0, 0);
        }
    }

    // bias + store f32
    #pragma unroll
    for (int nj = 0; nj < 8; ++nj) {
        int col = nj * 16 + llo;
        float bv = b2[col];
        #pragma unroll
        for (int mi = 0; mi < 2; ++mi) {
            #pragma unroll
            for (int r = 0; r < 4; ++r) {
                int row = row0 + wrow0 + mi * 16 + lhi * 4 + r;
                if (row < n_rows)
                    out[(size_t)row * DD + col] = acc[mi][nj][r] + bv;
            }
        }
    }
}

extern "C" void kernel_launch(void* const* d_in, const int* in_sizes, int n_in,
                              void* d_out, int out_size, void* d_ws, size_t ws_size,
                              hipStream_t stream) {
    const float* x1  = (const float*)d_in[0];
    const int*   adj = (const int*)d_in[1];
    const float* W1  = (const float*)d_in[2];
    const float* b1  = (const float*)d_in[3];
    const float* W2  = (const float*)d_in[4];
    const float* b2  = (const float*)d_in[5];
    float* out = (float*)d_out;

    const int n_nodes = in_sizes[0] / DD;   // 50000
    const int n_edges = in_sizes[1] / 2;    // 800000
    const int nb = (n_nodes + 255) / 256;   // 196 scan blocks

    // workspace layout (16B-aligned chunks first)
    char* ws = (char*)d_ws;
    size_t off = 0;
    u16* xin      = (u16*)(ws + off); off += (size_t)n_nodes * DD * sizeof(u16);   // 12.8MB
    u16* W1T      = (u16*)(ws + off); off += (size_t)DD * DD * sizeof(u16);        // 32KB
    u16* W2T      = (u16*)(ws + off); off += (size_t)DD * DD * sizeof(u16);        // 32KB
    int* csr_src  = (int*)(ws + off); off += (size_t)n_edges * sizeof(int);        // 3.2MB
    int* row_start= (int*)(ws + off); off += (size_t)(n_nodes + 1) * sizeof(int);
    int* cursor   = (int*)(ws + off); off += (size_t)n_nodes * sizeof(int);
    int* counts   = (int*)(ws + off); off += (size_t)n_nodes * sizeof(int);
    int* block_sums=(int*)(ws + off); off += 256 * sizeof(int);
    int* block_off= (int*)(ws + off); off += 256 * sizeof(int);

    hipMemsetAsync(counts, 0, (size_t)n_nodes * sizeof(int), stream);
    wprep_k<<<16, 256, 0, stream>>>(W1, W2, W1T, W2T);

    int eb = (n_edges + 255) / 256;
    hist_k<<<eb, 256, 0, stream>>>(adj, counts, n_edges, n_nodes);
    reduce_counts_k<<<nb, 256, 0, stream>>>(counts, block_sums, n_nodes);
    scan_sums_k<<<1, 256, 0, stream>>>(block_sums, block_off, row_start, nb, n_nodes);
    scan_write_k<<<nb, 256, 0, stream>>>(counts, block_off, row_start, cursor, n_nodes);
    fill_k<<<eb, 256, 0, stream>>>(adj, cursor, csr_src, n_edges, n_nodes);

    gather_max_k<<<(n_nodes + 7) / 8, 256, 0, stream>>>(x1, row_start, csr_src, xin, n_nodes);
    mlp_mfma_k<<<(n_nodes + ROWS - 1) / ROWS, 256, 0, stream>>>(
        xin, W1T, b1, W2T, b2, out, n_nodes);
}

// Round 4
// 167.711 us; speedup vs baseline: 2.7521x; 1.0870x over previous
//
#include <hip/hip_runtime.h>
#include <stdint.h>
#include <math.h>

#define DD 128
#define ROWS 128   // rows per MLP block

typedef unsigned short u16;
typedef unsigned int   u32;
typedef __attribute__((ext_vector_type(8))) short bf16x8;
typedef __attribute__((ext_vector_type(4))) float f32x4;

__device__ __forceinline__ u16 f2bf(float f) {   // RNE f32 -> bf16
    u32 u = __float_as_uint(f);
    return (u16)((u + 0x7fffu + ((u >> 16) & 1u)) >> 16);
}
__device__ __forceinline__ float bf_lo(u32 u) { return __uint_as_float(u << 16); }
__device__ __forceinline__ float bf_hi(u32 u) { return __uint_as_float(u & 0xffff0000u); }

// T2 swizzle: byte offset within a [row][256B] tile, XOR bits 4-6 by row&7
__device__ __forceinline__ int swz(int row, int byte_in_row) {
    return row * 256 + (byte_in_row ^ ((row & 7) << 4));
}

// ============ fused: x1->bf16 cvt + dst histogram + W prep ============
// blocks [0, nb_cvt): thread t converts 8 f32 and histograms edge t.
// last block: converts W1,W2 -> bf16 transposed [c][k], pre-swizzled.
__global__ __launch_bounds__(256) void pre_k(
    const float* __restrict__ x1, const int* __restrict__ adj,
    u16* __restrict__ x1bf, int* __restrict__ counts,
    const float* __restrict__ W1, const float* __restrict__ W2,
    u16* __restrict__ W1T, u16* __restrict__ W2T,
    int n_nodes, int n_edges)
{
    if ((int)blockIdx.x == (int)gridDim.x - 1) {   // weight prep
        for (int t = threadIdx.x; t < 4096; t += 256) {
            int m = t >> 11;
            int idx = t & 2047;
            int c = idx >> 4, k8 = idx & 15;
            const float* W = m ? W2 : W1;
            u16* WT = m ? W2T : W1T;
            u16 tmp[8];
            #pragma unroll
            for (int j = 0; j < 8; ++j) tmp[j] = f2bf(W[(k8 * 8 + j) * DD + c]);
            uint4 v;
            v.x = (u32)tmp[0] | ((u32)tmp[1] << 16);
            v.y = (u32)tmp[2] | ((u32)tmp[3] << 16);
            v.z = (u32)tmp[4] | ((u32)tmp[5] << 16);
            v.w = (u32)tmp[6] | ((u32)tmp[7] << 16);
            *(uint4*)((char*)WT + swz(c, k8 * 16)) = v;
        }
        return;
    }
    int t = blockIdx.x * 256 + threadIdx.x;
    int n_cvt = n_nodes * 16;          // uint4 stores (8 bf16 each)
    if (t < n_cvt) {
        const float4* x4 = (const float4*)x1;
        float4 a = x4[(size_t)t * 2];
        float4 b = x4[(size_t)t * 2 + 1];
        uint4 v;
        v.x = (u32)f2bf(a.x) | ((u32)f2bf(a.y) << 16);
        v.y = (u32)f2bf(a.z) | ((u32)f2bf(a.w) << 16);
        v.z = (u32)f2bf(b.x) | ((u32)f2bf(b.y) << 16);
        v.w = (u32)f2bf(b.z) | ((u32)f2bf(b.w) << 16);
        ((uint4*)x1bf)[t] = v;
    }
    if (t < n_edges) {
        int dst = adj[n_edges + t];
        if ((unsigned)dst < (unsigned)n_nodes) atomicAdd(&counts[dst], 1);
    }
}

// ============ scan (hierarchical) ============

__global__ __launch_bounds__(256) void reduce_counts_k(
    const int* __restrict__ counts, int* __restrict__ block_sums, int n)
{
    int i = blockIdx.x * 256 + threadIdx.x;
    int v = (i < n) ? counts[i] : 0;
    #pragma unroll
    for (int off = 32; off >= 1; off >>= 1) v += __shfl_down(v, off);
    __shared__ int ws[4];
    if ((threadIdx.x & 63) == 0) ws[threadIdx.x >> 6] = v;
    __syncthreads();
    if (threadIdx.x == 0) block_sums[blockIdx.x] = ws[0] + ws[1] + ws[2] + ws[3];
}

__global__ __launch_bounds__(256) void scan_sums_k(
    const int* __restrict__ block_sums, int* __restrict__ block_off,
    int* __restrict__ row_start, int nb, int n)
{
    int tid = threadIdx.x, wid = tid >> 6, lane = tid & 63;
    int v = (tid < nb) ? block_sums[tid] : 0;
    int incl = v;
    #pragma unroll
    for (int off = 1; off < 64; off <<= 1) {
        int t = __shfl_up(incl, off);
        if (lane >= off) incl += t;
    }
    __shared__ int ws[4];
    if (lane == 63) ws[wid] = incl;
    __syncthreads();
    int woff = 0;
    #pragma unroll
    for (int j = 0; j < 4; ++j) if (j < wid) woff += ws[j];
    if (tid < nb) block_off[tid] = woff + incl - v;
    if (tid == 0) row_start[n] = ws[0] + ws[1] + ws[2] + ws[3];
}

__global__ __launch_bounds__(256) void scan_write_k(
    const int* __restrict__ counts, const int* __restrict__ block_off,
    int* __restrict__ row_start, int* __restrict__ cursor, int n)
{
    int tid = threadIdx.x, wid = tid >> 6, lane = tid & 63;
    int i = blockIdx.x * 256 + tid;
    int v = (i < n) ? counts[i] : 0;
    int incl = v;
    #pragma unroll
    for (int off = 1; off < 64; off <<= 1) {
        int t = __shfl_up(incl, off);
        if (lane >= off) incl += t;
    }
    __shared__ int ws[4];
    if (lane == 63) ws[wid] = incl;
    __syncthreads();
    int woff = 0;
    #pragma unroll
    for (int j = 0; j < 4; ++j) if (j < wid) woff += ws[j];
    int excl = block_off[blockIdx.x] + woff + incl - v;
    if (i < n) { row_start[i] = excl; cursor[i] = excl; }
}

__global__ __launch_bounds__(256) void fill_k(
    const int* __restrict__ adj, int* __restrict__ cursor,
    int* __restrict__ csr_src, int n_edges, int n_nodes)
{
    int e = blockIdx.x * 256 + threadIdx.x;
    if (e >= n_edges) return;
    int src = adj[e];
    int dst = adj[n_edges + e];
    if ((unsigned)src >= (unsigned)n_nodes) return;
    if ((unsigned)dst >= (unsigned)n_nodes) return;
    int slot = atomicAdd(&cursor[dst], 1);
    csr_src[slot] = src;
}

// ============ gather-max over bf16 rows + residual -> bf16 xin ============
// 16 nodes per 256-thread block; 16 lanes per node, uint4 (8 bf16) per lane.
__global__ __launch_bounds__(256) void gather_max_k(
    const u16* __restrict__ x1bf, const int* __restrict__ row_start,
    const int* __restrict__ csr_src, u16* __restrict__ xin, int n_nodes)
{
    int node = blockIdx.x * 16 + (threadIdx.x >> 4);
    int q = threadIdx.x & 15;          // uint4 index within 256B row
    if (node >= n_nodes) return;
    int s = row_start[node], e = row_start[node + 1];
    const uint4* xb = (const uint4*)x1bf;

    float m[4][8];
    #pragma unroll
    for (int j = 0; j < 4; ++j)
        #pragma unroll
        for (int k = 0; k < 8; ++k) m[j][k] = -INFINITY;

    int i = s;
    for (; i + 3 < e; i += 4) {
        int s0 = csr_src[i], s1 = csr_src[i+1], s2 = csr_src[i+2], s3 = csr_src[i+3];
        uint4 v0 = xb[(size_t)s0 * 16 + q];
        uint4 v1 = xb[(size_t)s1 * 16 + q];
        uint4 v2 = xb[(size_t)s2 * 16 + q];
        uint4 v3 = xb[(size_t)s3 * 16 + q];
        #define ACC(J, V) \
            m[J][0]=fmaxf(m[J][0],bf_lo(V.x)); m[J][1]=fmaxf(m[J][1],bf_hi(V.x)); \
            m[J][2]=fmaxf(m[J][2],bf_lo(V.y)); m[J][3]=fmaxf(m[J][3],bf_hi(V.y)); \
            m[J][4]=fmaxf(m[J][4],bf_lo(V.z)); m[J][5]=fmaxf(m[J][5],bf_hi(V.z)); \
            m[J][6]=fmaxf(m[J][6],bf_lo(V.w)); m[J][7]=fmaxf(m[J][7],bf_hi(V.w));
        ACC(0, v0) ACC(1, v1) ACC(2, v2) ACC(3, v3)
    }
    for (; i < e; ++i) {
        int s0 = csr_src[i];
        uint4 v0 = xb[(size_t)s0 * 16 + q];
        ACC(0, v0)
        #undef ACC
    }
    #pragma unroll
    for (int k = 0; k < 8; ++k)
        m[0][k] = fmaxf(fmaxf(m[0][k], m[1][k]), fmaxf(m[2][k], m[3][k]));

    uint4 sv = xb[(size_t)node * 16 + q];
    float r[8];
    r[0]=bf_lo(sv.x); r[1]=bf_hi(sv.x); r[2]=bf_lo(sv.y); r[3]=bf_hi(sv.y);
    r[4]=bf_lo(sv.z); r[5]=bf_hi(sv.z); r[6]=bf_lo(sv.w); r[7]=bf_hi(sv.w);
    if (s < e) {
        #pragma unroll
        for (int k = 0; k < 8; ++k) r[k] += m[0][k];
    }
    uint4 o;
    o.x = (u32)f2bf(r[0]) | ((u32)f2bf(r[1]) << 16);
    o.y = (u32)f2bf(r[2]) | ((u32)f2bf(r[3]) << 16);
    o.z = (u32)f2bf(r[4]) | ((u32)f2bf(r[5]) << 16);
    o.w = (u32)f2bf(r[6]) | ((u32)f2bf(r[7]) << 16);
    ((uint4*)xin)[(size_t)node * 16 + q] = o;
}

// ============ MFMA MLP: out = relu(xin@W1+b1)@W2+b2 ============
__global__ __launch_bounds__(256, 2) void mlp_mfma_k(
    const u16* __restrict__ xin,
    const u16* __restrict__ W1T, const float* __restrict__ b1,
    const u16* __restrict__ W2T, const float* __restrict__ b2,
    float* __restrict__ out, int n_rows)
{
    __shared__ uint4 sXq[ROWS * 16];   // 32KB swizzled bf16 [128][128], reused for h
    __shared__ uint4 sWq[128 * 16];    // 32KB swizzled bf16 W^T [c][k]
    char* sX = (char*)sXq;
    char* sW = (char*)sWq;

    const int tid  = threadIdx.x;
    const int wave = tid >> 6;
    const int lane = tid & 63;
    const int lhi  = lane >> 4, llo = lane & 15;
    const int row0 = blockIdx.x * ROWS;

    {
        const uint4* src = (const uint4*)xin;
        #pragma unroll
        for (int i = tid; i < ROWS * 16; i += 256) {
            int r = i >> 4, c8 = i & 15;
            uint4 v = make_uint4(0, 0, 0, 0);
            if (row0 + r < n_rows) v = src[(size_t)(row0 + r) * 16 + c8];
            *(uint4*)(sX + swz(r, c8 * 16)) = v;
        }
        const uint4* wsrc = (const uint4*)W1T;
        #pragma unroll
        for (int i = tid; i < 2048; i += 256) sWq[i] = wsrc[i];
    }
    __syncthreads();

    const int wrow0 = wave * 32;

    f32x4 acc[2][8];
    #pragma unroll
    for (int mi = 0; mi < 2; ++mi)
        #pragma unroll
        for (int nj = 0; nj < 8; ++nj)
            acc[mi][nj] = (f32x4){0.f, 0.f, 0.f, 0.f};

    #pragma unroll
    for (int kstep = 0; kstep < 4; ++kstep) {
        int kb = (kstep * 32 + lhi * 8) * 2;
        int ra = wrow0 + llo, rb = wrow0 + 16 + llo;
        bf16x8 a0 = *(const bf16x8*)(sX + swz(ra, kb));
        bf16x8 a1 = *(const bf16x8*)(sX + swz(rb, kb));
        #pragma unroll
        for (int nj = 0; nj < 8; ++nj) {
            int c = nj * 16 + llo;
            bf16x8 b = *(const bf16x8*)(sW + swz(c, kb));
            acc[0][nj] = __builtin_amdgcn_mfma_f32_16x16x32_bf16(a0, b, acc[0][nj], 0, 0, 0);
            acc[1][nj] = __builtin_amdgcn_mfma_f32_16x16x32_bf16(a1, b, acc[1][nj], 0, 0, 0);
        }
    }

    #pragma unroll
    for (int nj = 0; nj < 8; ++nj) {
        int col = nj * 16 + llo;
        float bv = b1[col];
        #pragma unroll
        for (int mi = 0; mi < 2; ++mi) {
            #pragma unroll
            for (int r = 0; r < 4; ++r) {
                int row = wrow0 + mi * 16 + lhi * 4 + r;
                float h = fmaxf(acc[mi][nj][r] + bv, 0.f);
                *(u16*)(sX + swz(row, col * 2)) = f2bf(h);
            }
        }
    }
    __syncthreads();

    {
        const uint4* wsrc = (const uint4*)W2T;
        #pragma unroll
        for (int i = tid; i < 2048; i += 256) sWq[i] = wsrc[i];
    }
    __syncthreads();

    #pragma unroll
    for (int mi = 0; mi < 2; ++mi)
        #pragma unroll
        for (int nj = 0; nj < 8; ++nj)
            acc[mi][nj] = (f32x4){0.f, 0.f, 0.f, 0.f};

    #pragma unroll
    for (int kstep = 0; kstep < 4; ++kstep) {
        int kb = (kstep * 32 + lhi * 8) * 2;
        int ra = wrow0 + llo, rb = wrow0 + 16 + llo;
        bf16x8 a0 = *(const bf16x8*)(sX + swz(ra, kb));
        bf16x8 a1 = *(const bf16x8*)(sX + swz(rb, kb));
        #pragma unroll
        for (int nj = 0; nj < 8; ++nj) {
            int c = nj * 16 + llo;
            bf16x8 b = *(const bf16x8*)(sW + swz(c, kb));
            acc[0][nj] = __builtin_amdgcn_mfma_f32_16x16x32_bf16(a0, b, acc[0][nj], 0, 0, 0);
            acc[1][nj] = __builtin_amdgcn_mfma_f32_16x16x32_bf16(a1, b, acc[1][nj], 0, 0, 0);
        }
    }

    #pragma unroll
    for (int nj = 0; nj < 8; ++nj) {
        int col = nj * 16 + llo;
        float bv = b2[col];
        #pragma unroll
        for (int mi = 0; mi < 2; ++mi) {
            #pragma unroll
            for (int r = 0; r < 4; ++r) {
                int row = row0 + wrow0 + mi * 16 + lhi * 4 + r;
                if (row < n_rows)
                    out[(size_t)row * DD + col] = acc[mi][nj][r] + bv;
            }
        }
    }
}

extern "C" void kernel_launch(void* const* d_in, const int* in_sizes, int n_in,
                              void* d_out, int out_size, void* d_ws, size_t ws_size,
                              hipStream_t stream) {
    const float* x1  = (const float*)d_in[0];
    const int*   adj = (const int*)d_in[1];
    const float* W1  = (const float*)d_in[2];
    const float* b1  = (const float*)d_in[3];
    const float* W2  = (const float*)d_in[4];
    const float* b2  = (const float*)d_in[5];
    float* out = (float*)d_out;

    const int n_nodes = in_sizes[0] / DD;   // 50000
    const int n_edges = in_sizes[1] / 2;    // 800000
    const int nb = (n_nodes + 255) / 256;   // scan blocks

    // x1bf lives in d_out (dead until mlp overwrites it; strict stream order
    // cvt -> gather -> mlp makes this safe, and cvt rewrites it every call).
    u16* x1bf = (u16*)d_out;

    // workspace layout
    char* ws = (char*)d_ws;
    size_t off = 0;
    u16* xin      = (u16*)(ws + off); off += (size_t)n_nodes * DD * sizeof(u16);   // 12.8MB
    u16* W1T      = (u16*)(ws + off); off += (size_t)DD * DD * sizeof(u16);        // 32KB
    u16* W2T      = (u16*)(ws + off); off += (size_t)DD * DD * sizeof(u16);        // 32KB
    int* csr_src  = (int*)(ws + off); off += (size_t)n_edges * sizeof(int);        // 3.2MB
    int* row_start= (int*)(ws + off); off += (size_t)(n_nodes + 1) * sizeof(int);
    int* cursor   = (int*)(ws + off); off += (size_t)n_nodes * sizeof(int);
    int* counts   = (int*)(ws + off); off += (size_t)n_nodes * sizeof(int);
    int* block_sums=(int*)(ws + off); off += 256 * sizeof(int);
    int* block_off= (int*)(ws + off); off += 256 * sizeof(int);

    hipMemsetAsync(counts, 0, (size_t)n_nodes * sizeof(int), stream);

    int ncvt_blk = (n_nodes * 16 + 255) / 256;
    int eb = (n_edges + 255) / 256;
    int pre_blk = (ncvt_blk > eb ? ncvt_blk : eb) + 1;   // +1 block for weight prep
    pre_k<<<pre_blk, 256, 0, stream>>>(x1, adj, x1bf, counts, W1, W2, W1T, W2T,
                                       n_nodes, n_edges);

    reduce_counts_k<<<nb, 256, 0, stream>>>(counts, block_sums, n_nodes);
    scan_sums_k<<<1, 256, 0, stream>>>(block_sums, block_off, row_start, nb, n_nodes);
    scan_write_k<<<nb, 256, 0, stream>>>(counts, block_off, row_start, cursor, n_nodes);
    fill_k<<<eb, 256, 0, stream>>>(adj, cursor, csr_src, n_edges, n_nodes);

    gather_max_k<<<(n_nodes + 15) / 16, 256, 0, stream>>>(x1bf, row_start, csr_src, xin, n_nodes);
    mlp_mfma_k<<<(n_nodes + ROWS - 1) / ROWS, 256, 0, stream>>>(
        xin, W1T, b1, W2T, b2, out, n_nodes);
}

// Round 5
// 165.230 us; speedup vs baseline: 2.7934x; 1.0150x over previous
//
#include <hip/hip_runtime.h>
#include <stdint.h>
#include <math.h>

#define DD 128
#define ROWS 128   // rows per MLP block
#define NREP 8     // CSR counter replicas (contention spreading)

typedef unsigned short u16;
typedef unsigned int   u32;
typedef __attribute__((ext_vector_type(8))) short bf16x8;
typedef __attribute__((ext_vector_type(4))) float f32x4;

__device__ __forceinline__ u16 f2bf(float f) {   // RNE f32 -> bf16
    u32 u = __float_as_uint(f);
    return (u16)((u + 0x7fffu + ((u >> 16) & 1u)) >> 16);
}
__device__ __forceinline__ float bf_lo(u32 u) { return __uint_as_float(u << 16); }
__device__ __forceinline__ float bf_hi(u32 u) { return __uint_as_float(u & 0xffff0000u); }

// T2 swizzle: byte offset within a [row][256B] tile, XOR bits 4-6 by row&7
__device__ __forceinline__ int swz(int row, int byte_in_row) {
    return row * 256 + (byte_in_row ^ ((row & 7) << 4));
}

// ============ fused: x1->bf16 cvt + replicated dst histogram + W prep ============
// counts layout: replica-major cnt[r*N + node] -> contended lines spread 8x.
__global__ __launch_bounds__(256) void pre_k(
    const float* __restrict__ x1, const int* __restrict__ adj,
    u16* __restrict__ x1bf, int* __restrict__ counts,
    const float* __restrict__ W1, const float* __restrict__ W2,
    u16* __restrict__ W1T, u16* __restrict__ W2T,
    int n_nodes, int n_edges)
{
    if ((int)blockIdx.x == (int)gridDim.x - 1) {   // weight prep
        for (int t = threadIdx.x; t < 4096; t += 256) {
            int m = t >> 11;
            int idx = t & 2047;
            int c = idx >> 4, k8 = idx & 15;
            const float* W = m ? W2 : W1;
            u16* WT = m ? W2T : W1T;
            u16 tmp[8];
            #pragma unroll
            for (int j = 0; j < 8; ++j) tmp[j] = f2bf(W[(k8 * 8 + j) * DD + c]);
            uint4 v;
            v.x = (u32)tmp[0] | ((u32)tmp[1] << 16);
            v.y = (u32)tmp[2] | ((u32)tmp[3] << 16);
            v.z = (u32)tmp[4] | ((u32)tmp[5] << 16);
            v.w = (u32)tmp[6] | ((u32)tmp[7] << 16);
            *(uint4*)((char*)WT + swz(c, k8 * 16)) = v;
        }
        return;
    }
    int t = blockIdx.x * 256 + threadIdx.x;
    int n_cvt = n_nodes * 16;          // uint4 stores (8 bf16 each)
    if (t < n_cvt) {
        const float4* x4 = (const float4*)x1;
        float4 a = x4[(size_t)t * 2];
        float4 b = x4[(size_t)t * 2 + 1];
        uint4 v;
        v.x = (u32)f2bf(a.x) | ((u32)f2bf(a.y) << 16);
        v.y = (u32)f2bf(a.z) | ((u32)f2bf(a.w) << 16);
        v.z = (u32)f2bf(b.x) | ((u32)f2bf(b.y) << 16);
        v.w = (u32)f2bf(b.z) | ((u32)f2bf(b.w) << 16);
        ((uint4*)x1bf)[t] = v;
    }
    if (t < n_edges) {
        int src = adj[t];
        int dst = adj[n_edges + t];
        if ((unsigned)src < (unsigned)n_nodes && (unsigned)dst < (unsigned)n_nodes)
            atomicAdd(&counts[(t & (NREP - 1)) * n_nodes + dst], 1);
    }
}

// ============ hierarchical scan over semantic order i = node*8 + r ============
// reads are replica-major cnt[r*N+n] (coalesced per r); 2048 semantic elems/block.

__global__ __launch_bounds__(256) void reduce_k(
    const int* __restrict__ counts, int* __restrict__ block_sums, int n_nodes)
{
    int n = blockIdx.x * 256 + threadIdx.x;
    int s = 0;
    if (n < n_nodes) {
        #pragma unroll
        for (int r = 0; r < NREP; ++r) s += counts[r * n_nodes + n];
    }
    #pragma unroll
    for (int off = 32; off >= 1; off >>= 1) s += __shfl_down(s, off);
    __shared__ int ws[4];
    if ((threadIdx.x & 63) == 0) ws[threadIdx.x >> 6] = s;
    __syncthreads();
    if (threadIdx.x == 0) block_sums[blockIdx.x] = ws[0] + ws[1] + ws[2] + ws[3];
}

__global__ __launch_bounds__(256) void scan_sums_k(
    const int* __restrict__ block_sums, int* __restrict__ block_off,
    int* __restrict__ row_start, int nb, int total_idx)
{
    int tid = threadIdx.x, wid = tid >> 6, lane = tid & 63;
    int v = (tid < nb) ? block_sums[tid] : 0;
    int incl = v;
    #pragma unroll
    for (int off = 1; off < 64; off <<= 1) {
        int t = __shfl_up(incl, off);
        if (lane >= off) incl += t;
    }
    __shared__ int ws[4];
    if (lane == 63) ws[wid] = incl;
    __syncthreads();
    int woff = 0;
    #pragma unroll
    for (int j = 0; j < 4; ++j) if (j < wid) woff += ws[j];
    if (tid < nb) block_off[tid] = woff + incl - v;
    if (tid == 0) row_start[total_idx] = ws[0] + ws[1] + ws[2] + ws[3];
}

// writes row_start (node-major, coalesced uint4 x2) and cursor (replica-major)
__global__ __launch_bounds__(256) void scan_write_k(
    const int* __restrict__ counts, const int* __restrict__ block_off,
    int* __restrict__ row_start, int* __restrict__ cursor, int n_nodes)
{
    int tid = threadIdx.x, wid = tid >> 6, lane = tid & 63;
    int n = blockIdx.x * 256 + tid;
    int v[NREP];
    int tsum = 0;
    #pragma unroll
    for (int r = 0; r < NREP; ++r) {
        v[r] = (n < n_nodes) ? counts[r * n_nodes + n] : 0;
        tsum += v[r];
    }
    int incl = tsum;
    #pragma unroll
    for (int off = 1; off < 64; off <<= 1) {
        int t = __shfl_up(incl, off);
        if (lane >= off) incl += t;
    }
    __shared__ int ws[4];
    if (lane == 63) ws[wid] = incl;
    __syncthreads();
    int woff = 0;
    #pragma unroll
    for (int j = 0; j < 4; ++j) if (j < wid) woff += ws[j];
    if (n < n_nodes) {
        int base = block_off[blockIdx.x] + woff + incl - tsum;
        int rs[NREP];
        #pragma unroll
        for (int r = 0; r < NREP; ++r) { rs[r] = base; base += v[r]; }
        uint4 a, b;
        a.x = rs[0]; a.y = rs[1]; a.z = rs[2]; a.w = rs[3];
        b.x = rs[4]; b.y = rs[5]; b.z = rs[6]; b.w = rs[7];
        *(uint4*)&row_start[(size_t)n * NREP]     = a;
        *(uint4*)&row_start[(size_t)n * NREP + 4] = b;
        #pragma unroll
        for (int r = 0; r < NREP; ++r) cursor[r * n_nodes + n] = rs[r];
    }
}

__global__ __launch_bounds__(256) void fill_k(
    const int* __restrict__ adj, int* __restrict__ cursor,
    int* __restrict__ csr_src, int n_edges, int n_nodes)
{
    int e = blockIdx.x * 256 + threadIdx.x;
    if (e >= n_edges) return;
    int src = adj[e];
    int dst = adj[n_edges + e];
    if ((unsigned)src >= (unsigned)n_nodes) return;
    if ((unsigned)dst >= (unsigned)n_nodes) return;
    int slot = atomicAdd(&cursor[(e & (NREP - 1)) * n_nodes + dst], 1);
    csr_src[slot] = src;
}

// ============ gather-max over bf16 rows + residual -> bf16 xin ============
// 16 nodes per 256-thread block; 16 lanes per node, uint4 (8 bf16) per lane.
__global__ __launch_bounds__(256) void gather_max_k(
    const u16* __restrict__ x1bf, const int* __restrict__ row_start,
    const int* __restrict__ csr_src, u16* __restrict__ xin, int n_nodes)
{
    int node = blockIdx.x * 16 + (threadIdx.x >> 4);
    int q = threadIdx.x & 15;          // uint4 index within 256B row
    if (node >= n_nodes) return;
    int s = row_start[(size_t)node * NREP];
    int e = row_start[(size_t)node * NREP + NREP];
    const uint4* xb = (const uint4*)x1bf;

    float m[4][8];
    #pragma unroll
    for (int j = 0; j < 4; ++j)
        #pragma unroll
        for (int k = 0; k < 8; ++k) m[j][k] = -INFINITY;

    int i = s;
    for (; i + 3 < e; i += 4) {
        int s0 = csr_src[i], s1 = csr_src[i+1], s2 = csr_src[i+2], s3 = csr_src[i+3];
        uint4 v0 = xb[(size_t)s0 * 16 + q];
        uint4 v1 = xb[(size_t)s1 * 16 + q];
        uint4 v2 = xb[(size_t)s2 * 16 + q];
        uint4 v3 = xb[(size_t)s3 * 16 + q];
        #define ACC(J, V) \
            m[J][0]=fmaxf(m[J][0],bf_lo(V.x)); m[J][1]=fmaxf(m[J][1],bf_hi(V.x)); \
            m[J][2]=fmaxf(m[J][2],bf_lo(V.y)); m[J][3]=fmaxf(m[J][3],bf_hi(V.y)); \
            m[J][4]=fmaxf(m[J][4],bf_lo(V.z)); m[J][5]=fmaxf(m[J][5],bf_hi(V.z)); \
            m[J][6]=fmaxf(m[J][6],bf_lo(V.w)); m[J][7]=fmaxf(m[J][7],bf_hi(V.w));
        ACC(0, v0) ACC(1, v1) ACC(2, v2) ACC(3, v3)
    }
    for (; i < e; ++i) {
        int s0 = csr_src[i];
        uint4 v0 = xb[(size_t)s0 * 16 + q];
        ACC(0, v0)
        #undef ACC
    }
    #pragma unroll
    for (int k = 0; k < 8; ++k)
        m[0][k] = fmaxf(fmaxf(m[0][k], m[1][k]), fmaxf(m[2][k], m[3][k]));

    uint4 sv = xb[(size_t)node * 16 + q];
    float r[8];
    r[0]=bf_lo(sv.x); r[1]=bf_hi(sv.x); r[2]=bf_lo(sv.y); r[3]=bf_hi(sv.y);
    r[4]=bf_lo(sv.z); r[5]=bf_hi(sv.z); r[6]=bf_lo(sv.w); r[7]=bf_hi(sv.w);
    if (s < e) {
        #pragma unroll
        for (int k = 0; k < 8; ++k) r[k] += m[0][k];
    }
    uint4 o;
    o.x = (u32)f2bf(r[0]) | ((u32)f2bf(r[1]) << 16);
    o.y = (u32)f2bf(r[2]) | ((u32)f2bf(r[3]) << 16);
    o.z = (u32)f2bf(r[4]) | ((u32)f2bf(r[5]) << 16);
    o.w = (u32)f2bf(r[6]) | ((u32)f2bf(r[7]) << 16);
    ((uint4*)xin)[(size_t)node * 16 + q] = o;
}

// ============ MFMA MLP: out = relu(xin@W1+b1)@W2+b2 ============
__global__ __launch_bounds__(256, 2) void mlp_mfma_k(
    const u16* __restrict__ xin,
    const u16* __restrict__ W1T, const float* __restrict__ b1,
    const u16* __restrict__ W2T, const float* __restrict__ b2,
    float* __restrict__ out, int n_rows)
{
    __shared__ uint4 sXq[ROWS * 16];   // 32KB swizzled bf16 [128][128], reused for h
    __shared__ uint4 sWq[128 * 16];    // 32KB swizzled bf16 W^T [c][k]
    char* sX = (char*)sXq;
    char* sW = (char*)sWq;

    const int tid  = threadIdx.x;
    const int wave = tid >> 6;
    const int lane = tid & 63;
    const int lhi  = lane >> 4, llo = lane & 15;
    const int row0 = blockIdx.x * ROWS;

    {
        const uint4* src = (const uint4*)xin;
        #pragma unroll
        for (int i = tid; i < ROWS * 16; i += 256) {
            int r = i >> 4, c8 = i & 15;
            uint4 v = make_uint4(0, 0, 0, 0);
            if (row0 + r < n_rows) v = src[(size_t)(row0 + r) * 16 + c8];
            *(uint4*)(sX + swz(r, c8 * 16)) = v;
        }
        const uint4* wsrc = (const uint4*)W1T;
        #pragma unroll
        for (int i = tid; i < 2048; i += 256) sWq[i] = wsrc[i];
    }
    __syncthreads();

    const int wrow0 = wave * 32;

    f32x4 acc[2][8];
    #pragma unroll
    for (int mi = 0; mi < 2; ++mi)
        #pragma unroll
        for (int nj = 0; nj < 8; ++nj)
            acc[mi][nj] = (f32x4){0.f, 0.f, 0.f, 0.f};

    #pragma unroll
    for (int kstep = 0; kstep < 4; ++kstep) {
        int kb = (kstep * 32 + lhi * 8) * 2;
        int ra = wrow0 + llo, rb = wrow0 + 16 + llo;
        bf16x8 a0 = *(const bf16x8*)(sX + swz(ra, kb));
        bf16x8 a1 = *(const bf16x8*)(sX + swz(rb, kb));
        #pragma unroll
        for (int nj = 0; nj < 8; ++nj) {
            int c = nj * 16 + llo;
            bf16x8 b = *(const bf16x8*)(sW + swz(c, kb));
            acc[0][nj] = __builtin_amdgcn_mfma_f32_16x16x32_bf16(a0, b, acc[0][nj], 0, 0, 0);
            acc[1][nj] = __builtin_amdgcn_mfma_f32_16x16x32_bf16(a1, b, acc[1][nj], 0, 0, 0);
        }
    }

    #pragma unroll
    for (int nj = 0; nj < 8; ++nj) {
        int col = nj * 16 + llo;
        float bv = b1[col];
        #pragma unroll
        for (int mi = 0; mi < 2; ++mi) {
            #pragma unroll
            for (int r = 0; r < 4; ++r) {
                int row = wrow0 + mi * 16 + lhi * 4 + r;
                float h = fmaxf(acc[mi][nj][r] + bv, 0.f);
                *(u16*)(sX + swz(row, col * 2)) = f2bf(h);
            }
        }
    }
    __syncthreads();

    {
        const uint4* wsrc = (const uint4*)W2T;
        #pragma unroll
        for (int i = tid; i < 2048; i += 256) sWq[i] = wsrc[i];
    }
    __syncthreads();

    #pragma unroll
    for (int mi = 0; mi < 2; ++mi)
        #pragma unroll
        for (int nj = 0; nj < 8; ++nj)
            acc[mi][nj] = (f32x4){0.f, 0.f, 0.f, 0.f};

    #pragma unroll
    for (int kstep = 0; kstep < 4; ++kstep) {
        int kb = (kstep * 32 + lhi * 8) * 2;
        int ra = wrow0 + llo, rb = wrow0 + 16 + llo;
        bf16x8 a0 = *(const bf16x8*)(sX + swz(ra, kb));
        bf16x8 a1 = *(const bf16x8*)(sX + swz(rb, kb));
        #pragma unroll
        for (int nj = 0; nj < 8; ++nj) {
            int c = nj * 16 + llo;
            bf16x8 b = *(const bf16x8*)(sW + swz(c, kb));
            acc[0][nj] = __builtin_amdgcn_mfma_f32_16x16x32_bf16(a0, b, acc[0][nj], 0, 0, 0);
            acc[1][nj] = __builtin_amdgcn_mfma_f32_16x16x32_bf16(a1, b, acc[1][nj], 0, 0, 0);
        }
    }

    #pragma unroll
    for (int nj = 0; nj < 8; ++nj) {
        int col = nj * 16 + llo;
        float bv = b2[col];
        #pragma unroll
        for (int mi = 0; mi < 2; ++mi) {
            #pragma unroll
            for (int r = 0; r < 4; ++r) {
                int row = row0 + wrow0 + mi * 16 + lhi * 4 + r;
                if (row < n_rows)
                    out[(size_t)row * DD + col] = acc[mi][nj][r] + bv;
            }
        }
    }
}

extern "C" void kernel_launch(void* const* d_in, const int* in_sizes, int n_in,
                              void* d_out, int out_size, void* d_ws, size_t ws_size,
                              hipStream_t stream) {
    const float* x1  = (const float*)d_in[0];
    const int*   adj = (const int*)d_in[1];
    const float* W1  = (const float*)d_in[2];
    const float* b1  = (const float*)d_in[3];
    const float* W2  = (const float*)d_in[4];
    const float* b2  = (const float*)d_in[5];
    float* out = (float*)d_out;

    const int n_nodes = in_sizes[0] / DD;   // 50000
    const int n_edges = in_sizes[1] / 2;    // 800000
    const int nb = (n_nodes + 255) / 256;   // 196 scan blocks (2048 semantic elems each)

    // x1bf lives in d_out (dead until mlp overwrites it; strict stream order
    // cvt -> gather -> mlp makes this safe, and cvt rewrites it every call).
    u16* x1bf = (u16*)d_out;

    // workspace layout (16B aligned chunks)
    char* ws = (char*)d_ws;
    size_t off = 0;
    auto align16 = [&off]() { off = (off + 15) & ~(size_t)15; };
    u16* xin      = (u16*)(ws + off); off += (size_t)n_nodes * DD * sizeof(u16);       // 12.8MB
    u16* W1T      = (u16*)(ws + off); off += (size_t)DD * DD * sizeof(u16);            // 32KB
    u16* W2T      = (u16*)(ws + off); off += (size_t)DD * DD * sizeof(u16);            // 32KB
    int* csr_src  = (int*)(ws + off); off += (size_t)n_edges * sizeof(int);            // 3.2MB
    int* row_start= (int*)(ws + off); off += ((size_t)n_nodes * NREP + 1) * sizeof(int); align16();  // 1.6MB
    int* cursor   = (int*)(ws + off); off += (size_t)n_nodes * NREP * sizeof(int);     // 1.6MB
    int* counts   = (int*)(ws + off); off += (size_t)n_nodes * NREP * sizeof(int);     // 1.6MB
    int* block_sums=(int*)(ws + off); off += 256 * sizeof(int);
    int* block_off= (int*)(ws + off); off += 256 * sizeof(int);

    hipMemsetAsync(counts, 0, (size_t)n_nodes * NREP * sizeof(int), stream);

    int ncvt_blk = (n_nodes * 16 + 255) / 256;
    int eb = (n_edges + 255) / 256;
    int pre_blk = (ncvt_blk > eb ? ncvt_blk : eb) + 1;   // +1 block for weight prep
    pre_k<<<pre_blk, 256, 0, stream>>>(x1, adj, x1bf, counts, W1, W2, W1T, W2T,
                                       n_nodes, n_edges);

    reduce_k<<<nb, 256, 0, stream>>>(counts, block_sums, n_nodes);
    scan_sums_k<<<1, 256, 0, stream>>>(block_sums, block_off, row_start, nb,
                                       n_nodes * NREP);
    scan_write_k<<<nb, 256, 0, stream>>>(counts, block_off, row_start, cursor, n_nodes);
    fill_k<<<eb, 256, 0, stream>>>(adj, cursor, csr_src, n_edges, n_nodes);

    gather_max_k<<<(n_nodes + 15) / 16, 256, 0, stream>>>(x1bf, row_start, csr_src, xin, n_nodes);
    mlp_mfma_k<<<(n_nodes + ROWS - 1) / ROWS, 256, 0, stream>>>(
        xin, W1T, b1, W2T, b2, out, n_nodes);
}